// Round 8
// baseline (238.148 us; speedup 1.0000x reference)
//
#include <hip/hip_runtime.h>
#include <stdint.h>

typedef uint32_t u32;
typedef __attribute__((ext_vector_type(8))) short short8;  // 8 bf16 (4 VGPRs) - MFMA A/B frag
typedef __attribute__((ext_vector_type(4))) float f32x4;   // MFMA C/D frag
typedef __attribute__((ext_vector_type(4))) u32   u32x4;   // for nontemporal 16B stores

#define MREAL 50000
#define NBLK  784        // 8 XCD stripes x 98 blocks x 64 rows = 50176 (>= 50000)

__device__ __forceinline__ float bits2f(u32 b) { float f; __builtin_memcpy(&f, &b, 4); return f; }
__device__ __forceinline__ float bf2f(unsigned short h) { return bits2f(((u32)h) << 16); }
__device__ __forceinline__ unsigned short f2bf(float f) {
    u32 u; __builtin_memcpy(&u, &f, 4);
    u32 r = u + 0x7FFFu + ((u >> 16) & 1u);   // RNE
    return (unsigned short)(r >> 16);
}
__device__ __forceinline__ void addbf8(uint4 v, float a[8]) {
    a[0] += bits2f(v.x << 16); a[1] += bits2f(v.x & 0xFFFF0000u);
    a[2] += bits2f(v.y << 16); a[3] += bits2f(v.y & 0xFFFF0000u);
    a[4] += bits2f(v.z << 16); a[5] += bits2f(v.z & 0xFFFF0000u);
    a[6] += bits2f(v.w << 16); a[7] += bits2f(v.w & 0xFFFF0000u);
}
// Non-temporal 16B store via clang ext-vector (builtin rejects HIP_vector_type).
__device__ __forceinline__ void nt_store16(void* p, uint4 w) {
    u32x4 v = {w.x, w.y, w.z, w.w};
    __builtin_nontemporal_store(v, (u32x4*)p);
}

// ---------------------------------------------------------------------------
// Merged preprocessing. Blocks [0,784): x0 f32 -> bf16, XCD-STRIPED with the
// SAME r0 mapping as step_kernel, so the input stripe for step-1 is produced
// (and L2-cached) by its owning XCD. Round-6's linear cvt mapping put rows on
// XCDs round-robin in 8-row chunks: 7/8 of step-1's input reads started in
// the wrong L2. Blocks [784,2320): Bt/b2 prep (unchanged).
// ---------------------------------------------------------------------------
__global__ void preproc_kernel(const float* __restrict__ x0,
                               const float* __restrict__ Ws,
                               const float* __restrict__ bs,
                               const float* __restrict__ Wn,
                               const float* __restrict__ bn,
                               unsigned short* __restrict__ xbf,
                               unsigned short* __restrict__ Bt,
                               float* __restrict__ b2) {
    const int b = blockIdx.x;
    if (b < NBLK) {
        const long r0  = ((long)(b & 7) * 98 + (b >> 3)) * 64;
        const int colq = (threadIdx.x & 31) * 8;   // 8 f32 elems per lane
        const int rsub = threadIdx.x >> 5;         // 0..7
        #pragma unroll
        for (int it = 0; it < 8; ++it) {
            long row = r0 + it * 8 + rsub;
            if (row < MREAL) {
                const float* p = x0 + row * 256 + colq;
                float4 a = *(const float4*)p;
                float4 c = *(const float4*)(p + 4);
                uint4 o;
                o.x = (u32)f2bf(a.x) | ((u32)f2bf(a.y) << 16);
                o.y = (u32)f2bf(a.z) | ((u32)f2bf(a.w) << 16);
                o.z = (u32)f2bf(c.x) | ((u32)f2bf(c.y) << 16);
                o.w = (u32)f2bf(c.z) | ((u32)f2bf(c.w) << 16);
                *(uint4*)(xbf + row * 256 + colq) = o;   // normal store: WANT it in L2
            }
        }
    } else {
        int lin = (b - NBLK) * 256 + threadIdx.x;  // 3*16*256*32 = 393216 total
        int kkr = lin & 31;
        int n   = (lin >> 5) & 255;
        int kc  = (lin >> 13) & 15;
        int s   = lin >> 17;
        int kk  = kc * 32 + kkr;
        float v;
        if (kk < 256) v = Ws[(s * 256 + kk) * 256 + n] + (kk == n ? 1.0f : 0.0f);
        else          v = Wn[(s * 256 + (kk - 256)) * 256 + n] * (1.0f / 6.0f);
        Bt[lin] = f2bf(v);
        if (lin < 768) b2[lin] = bs[lin] + bn[lin];
    }
}

// ---------------------------------------------------------------------------
// One fused step: y = [x | neigh_sum] @ [Ws+I ; Wn/6] + (bs+bn); LN; ReLU.
// BM=64 rows/block, 4 waves, each wave 64x64 (4x4 MFMA).
//
// ROUND-15 (= round-14 with the nontemporal builtin fixed): round-6 structure
// (A fully from LDS; 49.8us/step) + NON-TEMPORAL output stores. Capacity
// analysis: per XCD the step's resident set was input 3.2 + output 3.2
// (dirty) + Bt 0.25 + nbr ~= 6.7 MB on a 4 MB L2 -- phase-staggered blocks'
// epilogue stores continuously evicted the input stripe other blocks' gathers
// were about to re-read (FETCH 17.8 MB/step of eviction-refetch at HBM
// latency). Output is never re-read within the step -> nt stores keep it out
// of L2; resident set drops to ~3.6 MB < 4 MB, so the gather's 7x per-row
// reuse stays L2-hit. Handoff to next step rides L3 (256 MB).
// Frozen learnings: occupancy dead lever (r2/r3); megafusion dead (r4:
// grid-barrier fences flush non-coherent per-XCD L2s); explicit SW pipelining
// dead (r5: compiler folds it); phase ORDER load-bearing for L2 (r1).
// ---------------------------------------------------------------------------
template <bool OUTF32>
__global__ __launch_bounds__(256, 2) void step_kernel(
    const unsigned short* __restrict__ src,   // x (bf16, 50000x256)
    void* __restrict__ dstv,                  // bf16 or f32, 50000x256
    const unsigned short* __restrict__ Bt,    // this step's [16][256][32] bf16
    const float* __restrict__ b2,             // [256] combined bias (f32)
    const float* __restrict__ lnS,            // [256] ln_scale f32
    const float* __restrict__ lnO,            // [256] ln_offset f32
    const int* __restrict__ nbr)              // [50000][6]
{
    __shared__ unsigned short Ax[64][264];    // x tile;  528 B stride (odd x16) = bank-spread
    __shared__ unsigned short AcNm[64][264];  // nm tile
    __shared__ float scr[640];                // LN scratch: srp[512] + srow[128]
    __shared__ int ids[384];                  // 64 rows x 6 neighbor indices

    const int t    = threadIdx.x;
    const int wv   = t >> 6;
    const int lane = t & 63;
    const int lo16 = lane & 15;
    const int quad = lane >> 4;
    // XCD-stripe mapping: blocks b with b&7==x land on XCD x (round-robin);
    // XCD x owns the contiguous row stripe, so gather stays in its 4 MB L2.
    const long r0  = ((long)(blockIdx.x & 7) * 98 + (blockIdx.x >> 3)) * 64;

    // ---------- P-1: stage neighbor indices (wave 0; int2 = 8B-aligned) ----------
    if (t < 64) {
        long rc = r0 + t;
        if (rc > MREAL - 1) rc = MREAL - 1;
        const int* nb = nbr + rc * 6;
        int2 a = *(const int2*)nb;
        int2 b = *(const int2*)(nb + 2);
        int2 c = *(const int2*)(nb + 4);
        ids[t * 6 + 0] = a.x; ids[t * 6 + 1] = a.y;
        ids[t * 6 + 2] = b.x; ids[t * 6 + 3] = b.y;
        ids[t * 6 + 4] = c.x; ids[t * 6 + 5] = c.y;
    }
    __syncthreads();

    // ---------- P0: gather neighbor sum + own-row x-tile stage (burst) ----------
    // Half-wave per row: lane (t&31) covers col (t&31)*8 (16 B); t>>5 picks the
    // row within the group of 8. Each wave-load = 2 full rows = 8 cache lines.
    {
        const int colq = (t & 31) * 8;
        const int rsub = t >> 5;               // 0..7
        #pragma unroll
        for (int it = 0; it < 8; ++it) {
            const int row = it * 8 + rsub;
            long rr = r0 + row;                // own row (same clamp as output guard)
            if (rr > MREAL - 1) rr = MREAL - 1;
            uint4 vo = *(const uint4*)(src + rr * 256 + colq);
            const int* idr = ids + row * 6;
            uint4 v0 = *(const uint4*)(src + (long)idr[0] * 256 + colq);
            uint4 v1 = *(const uint4*)(src + (long)idr[1] * 256 + colq);
            uint4 v2 = *(const uint4*)(src + (long)idr[2] * 256 + colq);
            uint4 v3 = *(const uint4*)(src + (long)idr[3] * 256 + colq);
            uint4 v4 = *(const uint4*)(src + (long)idr[4] * 256 + colq);
            uint4 v5 = *(const uint4*)(src + (long)idr[5] * 256 + colq);
            *(uint4*)&Ax[row][colq] = vo;
            float a[8] = {0, 0, 0, 0, 0, 0, 0, 0};
            addbf8(v0, a); addbf8(v1, a); addbf8(v2, a);
            addbf8(v3, a); addbf8(v4, a); addbf8(v5, a);
            uint4 o;
            o.x = (u32)f2bf(a[0]) | ((u32)f2bf(a[1]) << 16);
            o.y = (u32)f2bf(a[2]) | ((u32)f2bf(a[3]) << 16);
            o.z = (u32)f2bf(a[4]) | ((u32)f2bf(a[5]) << 16);
            o.w = (u32)f2bf(a[6]) | ((u32)f2bf(a[7]) << 16);
            *(uint4*)&AcNm[row][colq] = o;
        }
    }

    // Per-lane B base: n = wv*64 + nf*16 + lo16; element addr = n*32 + quad*8.
    const unsigned short* bbase = Bt + ((long)(wv * 64 + lo16) * 32 + quad * 8);

    const f32x4 zero4 = {0.f, 0.f, 0.f, 0.f};
    f32x4 acc[4][4];
    #pragma unroll
    for (int mf = 0; mf < 4; ++mf)
        #pragma unroll
        for (int nf = 0; nf < 4; ++nf) acc[mf][nf] = zero4;

    __syncthreads();                                   // Ax + AcNm ready

    // ---------- K-loop: barrier-free, fully unrolled (K = 512, 16x32) ----------
    // A entirely from LDS (x-half: Ax, nm-half: AcNm); only B from global (L2).
    #pragma unroll
    for (int k = 0; k < 16; ++k) {
        short8 afrag[4];
        if (k < 8) {
            #pragma unroll
            for (int mf = 0; mf < 4; ++mf)
                afrag[mf] = *(const short8*)&Ax[mf * 16 + lo16][k * 32 + quad * 8];
        } else {
            #pragma unroll
            for (int mf = 0; mf < 4; ++mf)
                afrag[mf] = *(const short8*)&AcNm[mf * 16 + lo16][(k - 8) * 32 + quad * 8];
        }
        short8 bfrag[4];
        #pragma unroll
        for (int nf = 0; nf < 4; ++nf)
            bfrag[nf] = *(const short8*)(bbase + k * 8192 + nf * 512);
        #pragma unroll
        for (int mf = 0; mf < 4; ++mf)
            #pragma unroll
            for (int nf = 0; nf < 4; ++nf)
                acc[mf][nf] = __builtin_amdgcn_mfma_f32_16x16x32_bf16(afrag[mf], bfrag[nf], acc[mf][nf], 0, 0, 0);
    }

    // ---------- Epilogue: bias + LN + ReLU, fully fused ----------
    __syncthreads();                                   // all K-loop LDS reads done
    float* srp  = scr;                                 // [64][4][2] partial sums
    float* srow = scr + 512;                           // [64][2] mean/rstd

    float biasc[4], gc[4], oc[4];
    #pragma unroll
    for (int nf = 0; nf < 4; ++nf) {
        int col = wv * 64 + nf * 16 + lo16;
        biasc[nf] = b2[col];
        gc[nf] = lnS[col];
        oc[nf] = lnO[col];
    }
    #pragma unroll
    for (int mf = 0; mf < 4; ++mf)
        #pragma unroll
        for (int nf = 0; nf < 4; ++nf) acc[mf][nf] += biasc[nf];

    #pragma unroll
    for (int mf = 0; mf < 4; ++mf) {
        float s1[4], s2[4];
        #pragma unroll
        for (int r = 0; r < 4; ++r) {
            float v0 = acc[mf][0][r], v1 = acc[mf][1][r], v2 = acc[mf][2][r], v3 = acc[mf][3][r];
            s1[r] = v0 + v1 + v2 + v3;
            s2[r] = v0 * v0 + v1 * v1 + v2 * v2 + v3 * v3;
        }
        #pragma unroll
        for (int d = 1; d < 16; d <<= 1) {
            #pragma unroll
            for (int r = 0; r < 4; ++r) {
                s1[r] += __shfl_xor(s1[r], d, 64);
                s2[r] += __shfl_xor(s2[r], d, 64);
            }
        }
        if (lo16 == 0) {
            int row = mf * 16 + quad * 4;
            #pragma unroll
            for (int r = 0; r < 4; ++r) {
                srp[(row + r) * 8 + wv * 2    ] = s1[r];
                srp[(row + r) * 8 + wv * 2 + 1] = s2[r];
            }
        }
    }
    __syncthreads();
    if (t < 64) {
        float S1 = 0.f, S2 = 0.f;
        #pragma unroll
        for (int w = 0; w < 4; ++w) { S1 += srp[t * 8 + w * 2]; S2 += srp[t * 8 + w * 2 + 1]; }
        float mean = S1 * (1.0f / 256.0f);
        float var  = S2 * (1.0f / 256.0f) - mean * mean;
        float rstd = rsqrtf(var + 1e-5f);
        srow[t * 2] = mean; srow[t * 2 + 1] = rstd;
    }
    __syncthreads();

    // Normalize into AcNm (flat [64][256] bf16, global layout) ...
    unsigned short* obuf = &AcNm[0][0];
    #pragma unroll
    for (int mf = 0; mf < 4; ++mf) {
        #pragma unroll
        for (int r = 0; r < 4; ++r) {
            int row = mf * 16 + quad * 4 + r;
            float mean = srow[row * 2], rstd = srow[row * 2 + 1];
            #pragma unroll
            for (int nf = 0; nf < 4; ++nf) {
                float v = (acc[mf][nf][r] - mean) * rstd * gc[nf] + oc[nf];
                v = fmaxf(v, 0.0f);
                obuf[row * 256 + wv * 64 + nf * 16 + lo16] = f2bf(v);
            }
        }
    }
    __syncthreads();

    // ... then store flat & coalesced, NON-TEMPORAL (never re-read this step;
    // keeps the input stripe L2-resident — handoff to next step rides L3).
    #pragma unroll
    for (int it = 0; it < 8; ++it) {
        const int e = it * 2048 + t * 8;               // tile element index (8 per lane, one row)
        const long rg = r0 + (e >> 8);
        if (rg < MREAL) {
            uint4 w = *(const uint4*)(obuf + e);
            if (OUTF32) {
                float* dp = (float*)dstv + r0 * 256 + e;
                uint4 lo, hi;
                lo.x = w.x << 16; lo.y = w.x & 0xFFFF0000u;
                lo.z = w.y << 16; lo.w = w.y & 0xFFFF0000u;
                hi.x = w.z << 16; hi.y = w.z & 0xFFFF0000u;
                hi.z = w.w << 16; hi.w = w.w & 0xFFFF0000u;
                nt_store16(dp, lo);
                nt_store16(dp + 4, hi);
            } else {
                nt_store16((unsigned short*)dstv + r0 * 256 + e, w);
            }
        }
    }
}

// ---------------------------------------------------------------------------
extern "C" void kernel_launch(void* const* d_in, const int* in_sizes, int n_in,
                              void* d_out, int out_size, void* d_ws, size_t ws_size,
                              hipStream_t stream) {
    const float* x0  = (const float*)d_in[0];  // 50000x256 f32
    const float* Ws  = (const float*)d_in[1];  // 3x256x256 f32
    const float* bs  = (const float*)d_in[2];  // 3x256 f32
    const float* Wn  = (const float*)d_in[3];  // 3x256x256 f32
    const float* bn  = (const float*)d_in[4];  // 3x256 f32
    const float* lnS = (const float*)d_in[5];  // 3x256 f32
    const float* lnO = (const float*)d_in[6];  // 3x256 f32
    const int* nbr   = (const int*)d_in[7];    // 50000x6 i32

    char* ws = (char*)d_ws;
    const size_t XBYTES = (size_t)MREAL * 256 * 2;               // 25,600,000 (bf16 state)
    unsigned short* xbf = (unsigned short*)ws;
    unsigned short* xA  = (unsigned short*)(ws + XBYTES);
    unsigned short* Bt  = (unsigned short*)(ws + 2 * XBYTES);    // 786,432 B
    float*          b2  = (float*)(ws + 2 * XBYTES + 786432);    // 3,072 B

    preproc_kernel<<<NBLK + 1536, 256, 0, stream>>>(x0, Ws, bs, Wn, bn, xbf, Bt, b2);
    step_kernel<false><<<NBLK, 256, 0, stream>>>(xbf, (void*)xA,  Bt,          b2,       lnS,       lnO,       nbr);
    step_kernel<false><<<NBLK, 256, 0, stream>>>(xA,  (void*)xbf, Bt + 131072, b2 + 256, lnS + 256, lnO + 256, nbr);
    step_kernel<true> <<<NBLK, 256, 0, stream>>>(xbf, d_out,      Bt + 262144, b2 + 512, lnS + 512, lnO + 512, nbr);
}

// Round 9
// 234.284 us; speedup vs baseline: 1.0165x; 1.0165x over previous
//
#include <hip/hip_runtime.h>
#include <stdint.h>

typedef uint32_t u32;
typedef __attribute__((ext_vector_type(8))) short short8;  // 8 bf16 (4 VGPRs) - MFMA A/B frag
typedef __attribute__((ext_vector_type(4))) float f32x4;   // MFMA C/D frag

#define MREAL 50000
#define NBLK  784        // 8 XCD stripes x 98 blocks x 64 rows = 50176 (>= 50000)

__device__ __forceinline__ float bits2f(u32 b) { float f; __builtin_memcpy(&f, &b, 4); return f; }
__device__ __forceinline__ float bf2f(unsigned short h) { return bits2f(((u32)h) << 16); }
__device__ __forceinline__ unsigned short f2bf(float f) {
    u32 u; __builtin_memcpy(&u, &f, 4);
    u32 r = u + 0x7FFFu + ((u >> 16) & 1u);   // RNE
    return (unsigned short)(r >> 16);
}
__device__ __forceinline__ void addbf8(uint4 v, float a[8]) {
    a[0] += bits2f(v.x << 16); a[1] += bits2f(v.x & 0xFFFF0000u);
    a[2] += bits2f(v.y << 16); a[3] += bits2f(v.y & 0xFFFF0000u);
    a[4] += bits2f(v.z << 16); a[5] += bits2f(v.z & 0xFFFF0000u);
    a[6] += bits2f(v.w << 16); a[7] += bits2f(v.w & 0xFFFF0000u);
}

// ---------------------------------------------------------------------------
// Prep: Bt[step][kc][n][kkr] = bf16 of B^T chunk-packed, B = [Ws + I ; Wn/6]
// (512x256 per step). b2 = bs + bn. The x0 cvt pass is GONE (round-16):
// step-1 reads x0 f32 directly and converts inline — deletes 76.8 MB of
// dedicated streaming plus one dispatch boundary.
// ---------------------------------------------------------------------------
__global__ void prep_kernel(const float* __restrict__ Ws,
                            const float* __restrict__ bs,
                            const float* __restrict__ Wn,
                            const float* __restrict__ bn,
                            unsigned short* __restrict__ Bt,
                            float* __restrict__ b2) {
    int lin = blockIdx.x * 256 + threadIdx.x;      // 3*16*256*32 = 393216 total
    int kkr = lin & 31;
    int n   = (lin >> 5) & 255;
    int kc  = (lin >> 13) & 15;
    int s   = lin >> 17;
    int kk  = kc * 32 + kkr;
    float v;
    if (kk < 256) v = Ws[(s * 256 + kk) * 256 + n] + (kk == n ? 1.0f : 0.0f);
    else          v = Wn[(s * 256 + (kk - 256)) * 256 + n] * (1.0f / 6.0f);
    Bt[lin] = f2bf(v);
    if (lin < 768) b2[lin] = bs[lin] + bn[lin];
}

// ---------------------------------------------------------------------------
// One fused step: y = [x | neigh_sum] @ [Ws+I ; Wn/6] + (bs+bn); LN; ReLU.
// BM=64 rows/block, 4 waves, each wave 64x64 (4x4 MFMA).
//
// ROUND-16: round-6 step code verbatim (best measured: 49.8us/step, A fully
// from LDS, normal stores — nt stores REVERTED: r8 showed WRITE 50->62 MB
// (no write-combining) and dur +4.5us for only -2.3 MB FETCH), plus
// template<INF32>: step-1 reads x0 in f32 and converts inline during the
// gather/stage (f32 path needs FEWER VALU ops — adds without bf16 unpack
// shifts). Kills the cvt dispatch (~13us) + one boundary (~15us).
// Frozen learnings: occupancy dead lever (r2/r3); megafusion dead (r4:
// grid-barrier fences flush non-coherent per-XCD L2s); explicit SW pipelining
// dead (r5: compiler folds it); phase ORDER load-bearing for L2 (r1);
// nt stores dead (r8).
// ---------------------------------------------------------------------------
template <bool INF32, bool OUTF32>
__global__ __launch_bounds__(256, 2) void step_kernel(
    const void* __restrict__ srcv,            // x (bf16 or f32, 50000x256)
    void* __restrict__ dstv,                  // bf16 or f32, 50000x256
    const unsigned short* __restrict__ Bt,    // this step's [16][256][32] bf16
    const float* __restrict__ b2,             // [256] combined bias (f32)
    const float* __restrict__ lnS,            // [256] ln_scale f32
    const float* __restrict__ lnO,            // [256] ln_offset f32
    const int* __restrict__ nbr)              // [50000][6]
{
    __shared__ unsigned short Ax[64][264];    // x tile;  528 B stride (odd x16) = bank-spread
    __shared__ unsigned short AcNm[64][264];  // nm tile
    __shared__ float scr[640];                // LN scratch: srp[512] + srow[128]
    __shared__ int ids[384];                  // 64 rows x 6 neighbor indices

    const int t    = threadIdx.x;
    const int wv   = t >> 6;
    const int lane = t & 63;
    const int lo16 = lane & 15;
    const int quad = lane >> 4;
    // XCD-stripe mapping: blocks b with b&7==x land on XCD x (round-robin);
    // XCD x owns the contiguous row stripe, so gather stays in its 4 MB L2.
    const long r0  = ((long)(blockIdx.x & 7) * 98 + (blockIdx.x >> 3)) * 64;

    // ---------- P-1: stage neighbor indices (wave 0; int2 = 8B-aligned) ----------
    if (t < 64) {
        long rc = r0 + t;
        if (rc > MREAL - 1) rc = MREAL - 1;
        const int* nb = nbr + rc * 6;
        int2 a = *(const int2*)nb;
        int2 b = *(const int2*)(nb + 2);
        int2 c = *(const int2*)(nb + 4);
        ids[t * 6 + 0] = a.x; ids[t * 6 + 1] = a.y;
        ids[t * 6 + 2] = b.x; ids[t * 6 + 3] = b.y;
        ids[t * 6 + 4] = c.x; ids[t * 6 + 5] = c.y;
    }
    __syncthreads();

    // ---------- P0: gather neighbor sum + own-row x-tile stage (burst) ----------
    // Half-wave per row: lane (t&31) covers elems (t&31)*8..+7; t>>5 picks the
    // row within the group of 8. bf16: 16 B/lane, f32: 32 B/lane (2x float4).
    {
        const int colq = (t & 31) * 8;         // element index (dtype-agnostic)
        const int rsub = t >> 5;               // 0..7
        #pragma unroll
        for (int it = 0; it < 8; ++it) {
            const int row = it * 8 + rsub;
            long rr = r0 + row;                // own row (same clamp as output guard)
            if (rr > MREAL - 1) rr = MREAL - 1;
            const int* idr = ids + row * 6;
            float a[8] = {0, 0, 0, 0, 0, 0, 0, 0};
            uint4 ax;
            if (INF32) {
                const float* sf = (const float*)srcv;
                float4 w0 = *(const float4*)(sf + rr * 256 + colq);
                float4 w1 = *(const float4*)(sf + rr * 256 + colq + 4);
                ax.x = (u32)f2bf(w0.x) | ((u32)f2bf(w0.y) << 16);
                ax.y = (u32)f2bf(w0.z) | ((u32)f2bf(w0.w) << 16);
                ax.z = (u32)f2bf(w1.x) | ((u32)f2bf(w1.y) << 16);
                ax.w = (u32)f2bf(w1.z) | ((u32)f2bf(w1.w) << 16);
                #pragma unroll
                for (int j = 0; j < 6; ++j) {
                    const float* np = sf + (long)idr[j] * 256 + colq;
                    float4 n0 = *(const float4*)np;
                    float4 n1 = *(const float4*)(np + 4);
                    a[0] += n0.x; a[1] += n0.y; a[2] += n0.z; a[3] += n0.w;
                    a[4] += n1.x; a[5] += n1.y; a[6] += n1.z; a[7] += n1.w;
                }
            } else {
                const unsigned short* sb = (const unsigned short*)srcv;
                ax = *(const uint4*)(sb + rr * 256 + colq);
                uint4 v0 = *(const uint4*)(sb + (long)idr[0] * 256 + colq);
                uint4 v1 = *(const uint4*)(sb + (long)idr[1] * 256 + colq);
                uint4 v2 = *(const uint4*)(sb + (long)idr[2] * 256 + colq);
                uint4 v3 = *(const uint4*)(sb + (long)idr[3] * 256 + colq);
                uint4 v4 = *(const uint4*)(sb + (long)idr[4] * 256 + colq);
                uint4 v5 = *(const uint4*)(sb + (long)idr[5] * 256 + colq);
                addbf8(v0, a); addbf8(v1, a); addbf8(v2, a);
                addbf8(v3, a); addbf8(v4, a); addbf8(v5, a);
            }
            *(uint4*)&Ax[row][colq] = ax;
            uint4 o;
            o.x = (u32)f2bf(a[0]) | ((u32)f2bf(a[1]) << 16);
            o.y = (u32)f2bf(a[2]) | ((u32)f2bf(a[3]) << 16);
            o.z = (u32)f2bf(a[4]) | ((u32)f2bf(a[5]) << 16);
            o.w = (u32)f2bf(a[6]) | ((u32)f2bf(a[7]) << 16);
            *(uint4*)&AcNm[row][colq] = o;
        }
    }

    // Per-lane B base: n = wv*64 + nf*16 + lo16; element addr = n*32 + quad*8.
    const unsigned short* bbase = Bt + ((long)(wv * 64 + lo16) * 32 + quad * 8);

    const f32x4 zero4 = {0.f, 0.f, 0.f, 0.f};
    f32x4 acc[4][4];
    #pragma unroll
    for (int mf = 0; mf < 4; ++mf)
        #pragma unroll
        for (int nf = 0; nf < 4; ++nf) acc[mf][nf] = zero4;

    __syncthreads();                                   // Ax + AcNm ready

    // ---------- K-loop: barrier-free, fully unrolled (K = 512, 16x32) ----------
    // A entirely from LDS (x-half: Ax, nm-half: AcNm); only B from global (L2).
    #pragma unroll
    for (int k = 0; k < 16; ++k) {
        short8 afrag[4];
        if (k < 8) {
            #pragma unroll
            for (int mf = 0; mf < 4; ++mf)
                afrag[mf] = *(const short8*)&Ax[mf * 16 + lo16][k * 32 + quad * 8];
        } else {
            #pragma unroll
            for (int mf = 0; mf < 4; ++mf)
                afrag[mf] = *(const short8*)&AcNm[mf * 16 + lo16][(k - 8) * 32 + quad * 8];
        }
        short8 bfrag[4];
        #pragma unroll
        for (int nf = 0; nf < 4; ++nf)
            bfrag[nf] = *(const short8*)(bbase + k * 8192 + nf * 512);
        #pragma unroll
        for (int mf = 0; mf < 4; ++mf)
            #pragma unroll
            for (int nf = 0; nf < 4; ++nf)
                acc[mf][nf] = __builtin_amdgcn_mfma_f32_16x16x32_bf16(afrag[mf], bfrag[nf], acc[mf][nf], 0, 0, 0);
    }

    // ---------- Epilogue: bias + LN + ReLU, fully fused ----------
    __syncthreads();                                   // all K-loop LDS reads done
    float* srp  = scr;                                 // [64][4][2] partial sums
    float* srow = scr + 512;                           // [64][2] mean/rstd

    float biasc[4], gc[4], oc[4];
    #pragma unroll
    for (int nf = 0; nf < 4; ++nf) {
        int col = wv * 64 + nf * 16 + lo16;
        biasc[nf] = b2[col];
        gc[nf] = lnS[col];
        oc[nf] = lnO[col];
    }
    #pragma unroll
    for (int mf = 0; mf < 4; ++mf)
        #pragma unroll
        for (int nf = 0; nf < 4; ++nf) acc[mf][nf] += biasc[nf];

    #pragma unroll
    for (int mf = 0; mf < 4; ++mf) {
        float s1[4], s2[4];
        #pragma unroll
        for (int r = 0; r < 4; ++r) {
            float v0 = acc[mf][0][r], v1 = acc[mf][1][r], v2 = acc[mf][2][r], v3 = acc[mf][3][r];
            s1[r] = v0 + v1 + v2 + v3;
            s2[r] = v0 * v0 + v1 * v1 + v2 * v2 + v3 * v3;
        }
        #pragma unroll
        for (int d = 1; d < 16; d <<= 1) {
            #pragma unroll
            for (int r = 0; r < 4; ++r) {
                s1[r] += __shfl_xor(s1[r], d, 64);
                s2[r] += __shfl_xor(s2[r], d, 64);
            }
        }
        if (lo16 == 0) {
            int row = mf * 16 + quad * 4;
            #pragma unroll
            for (int r = 0; r < 4; ++r) {
                srp[(row + r) * 8 + wv * 2    ] = s1[r];
                srp[(row + r) * 8 + wv * 2 + 1] = s2[r];
            }
        }
    }
    __syncthreads();
    if (t < 64) {
        float S1 = 0.f, S2 = 0.f;
        #pragma unroll
        for (int w = 0; w < 4; ++w) { S1 += srp[t * 8 + w * 2]; S2 += srp[t * 8 + w * 2 + 1]; }
        float mean = S1 * (1.0f / 256.0f);
        float var  = S2 * (1.0f / 256.0f) - mean * mean;
        float rstd = rsqrtf(var + 1e-5f);
        srow[t * 2] = mean; srow[t * 2 + 1] = rstd;
    }
    __syncthreads();

    // Normalize into AcNm (flat [64][256] bf16, global layout) ...
    unsigned short* obuf = &AcNm[0][0];
    #pragma unroll
    for (int mf = 0; mf < 4; ++mf) {
        #pragma unroll
        for (int r = 0; r < 4; ++r) {
            int row = mf * 16 + quad * 4 + r;
            float mean = srow[row * 2], rstd = srow[row * 2 + 1];
            #pragma unroll
            for (int nf = 0; nf < 4; ++nf) {
                float v = (acc[mf][nf][r] - mean) * rstd * gc[nf] + oc[nf];
                v = fmaxf(v, 0.0f);
                obuf[row * 256 + wv * 64 + nf * 16 + lo16] = f2bf(v);
            }
        }
    }
    __syncthreads();

    // ... then store flat & coalesced: 16 B/lane (bf16) or 32 B/lane (f32).
    #pragma unroll
    for (int it = 0; it < 8; ++it) {
        const int e = it * 2048 + t * 8;               // tile element index (8 per lane, one row)
        const long rg = r0 + (e >> 8);
        if (rg < MREAL) {
            uint4 w = *(const uint4*)(obuf + e);
            if (OUTF32) {
                float* dp = (float*)dstv + r0 * 256 + e;
                float4 f0, f1;
                f0.x = bits2f(w.x << 16); f0.y = bits2f(w.x & 0xFFFF0000u);
                f0.z = bits2f(w.y << 16); f0.w = bits2f(w.y & 0xFFFF0000u);
                f1.x = bits2f(w.z << 16); f1.y = bits2f(w.z & 0xFFFF0000u);
                f1.z = bits2f(w.w << 16); f1.w = bits2f(w.w & 0xFFFF0000u);
                *(float4*)dp = f0;
                *(float4*)(dp + 4) = f1;
            } else {
                *(uint4*)((unsigned short*)dstv + r0 * 256 + e) = w;
            }
        }
    }
}

// ---------------------------------------------------------------------------
extern "C" void kernel_launch(void* const* d_in, const int* in_sizes, int n_in,
                              void* d_out, int out_size, void* d_ws, size_t ws_size,
                              hipStream_t stream) {
    const float* x0  = (const float*)d_in[0];  // 50000x256 f32
    const float* Ws  = (const float*)d_in[1];  // 3x256x256 f32
    const float* bs  = (const float*)d_in[2];  // 3x256 f32
    const float* Wn  = (const float*)d_in[3];  // 3x256x256 f32
    const float* bn  = (const float*)d_in[4];  // 3x256 f32
    const float* lnS = (const float*)d_in[5];  // 3x256 f32
    const float* lnO = (const float*)d_in[6];  // 3x256 f32
    const int* nbr   = (const int*)d_in[7];    // 50000x6 i32

    char* ws = (char*)d_ws;
    const size_t XBYTES = (size_t)MREAL * 256 * 2;               // 25,600,000 (bf16 state)
    unsigned short* xbf = (unsigned short*)ws;
    unsigned short* xA  = (unsigned short*)(ws + XBYTES);
    unsigned short* Bt  = (unsigned short*)(ws + 2 * XBYTES);    // 786,432 B
    float*          b2  = (float*)(ws + 2 * XBYTES + 786432);    // 3,072 B

    prep_kernel<<<1536, 256, 0, stream>>>(Ws, bs, Wn, bn, Bt, b2);
    step_kernel<true,  false><<<NBLK, 256, 0, stream>>>(x0,  (void*)xA,  Bt,          b2,       lnS,       lnO,       nbr);
    step_kernel<false, false><<<NBLK, 256, 0, stream>>>(xA,  (void*)xbf, Bt + 131072, b2 + 256, lnS + 256, lnO + 256, nbr);
    step_kernel<false, true> <<<NBLK, 256, 0, stream>>>(xbf, d_out,      Bt + 262144, b2 + 512, lnS + 512, lnO + 512, nbr);
}